// Round 8
// baseline (1010.332 us; speedup 1.0000x reference)
//
#include <hip/hip_runtime.h>

// Problem constants
#define NDRUG 50000
#define NDIS  50000
#define RR    5
#define FF    128
#define EFFD  128
#define OUTD  64
#define EE    400000
#define NCOL  (RR * OUTD)        // 320 columns in fused g / out layout [n][r*64+o]
#define NB    (RR * NDIS)        // 250000 bins per direction
#define NEDGE (RR * EE)          // 2,000,000 edges per direction

// Two-level bucket sort
#define NBKT    196              // coarse buckets per (dir,r): dst>>8 (50000/256)
#define CAP     4096             // slot capacity per bucket (avg fill 2048, ~40 sigma headroom)
#define NGB     (2 * RR * NBKT)  // 1960 global buckets
#define QBKT    49               // buckets per dst-quarter (196 = 4*49)

// XCD partitioning for k_part: 8 partitions = dir(2) x dst-quarter(4)
#define NPART   8
#define NCHUNKE 64               // edge chunks per r
#define CHUNKE  (EE / NCHUNKE)   // 6250 edges per chunk

typedef unsigned short ushort_t;
typedef unsigned int uint_t;
typedef short short8 __attribute__((ext_vector_type(8)));
typedef float f32x4 __attribute__((ext_vector_type(4)));

// f32 -> bf16 round-to-nearest-even
static __device__ __forceinline__ ushort_t f2bf(float f) {
    uint_t u = __float_as_uint(f);
    uint_t r = (u + 0x7FFFu + ((u >> 16) & 1u)) >> 16;
    return (ushort_t)r;
}
static __device__ __forceinline__ float bf2f(ushort_t u) {
    return __uint_as_float(((uint_t)u) << 16);
}

// ---------------------------------------------------------------------------
// Kernel A: Mt[col][f] = bf16( sum_e (att[r,0]*basis[0,f,e]+att[r,1]*basis[1,f,e]) * fc_w[e,o] )
// ---------------------------------------------------------------------------
__global__ __launch_bounds__(256) void k_make_M(const float* __restrict__ att,
                                                const float* __restrict__ basis,
                                                const float* __restrict__ fcw,
                                                ushort_t* __restrict__ Mt) {
    int tid = blockIdx.x * 256 + threadIdx.x;
    if (tid >= RR * FF * OUTD) return;
    int r = tid / (FF * OUTD);
    int rem = tid - r * FF * OUTD;
    int f = rem >> 6;
    int o = rem & 63;
    float a0 = att[r * 2 + 0], a1 = att[r * 2 + 1];
    const float* b0 = basis + f * EFFD;
    const float* b1 = basis + FF * EFFD + f * EFFD;
    float acc = 0.f;
#pragma unroll 4
    for (int e = 0; e < EFFD; ++e) {
        float w = a0 * b0[e] + a1 * b1[e];
        acc += w * fcw[e * OUTD + o];
    }
    Mt[(size_t)(r * OUTD + o) * FF + f] = f2bf(acc);
}

// ---------------------------------------------------------------------------
// Kernel B (MFMA): g[n][col] = bf16( cj[n] * sum_k feat[n][k] * M[k][col] )
// ---------------------------------------------------------------------------
__global__ __launch_bounds__(256) void k_gemm(const float* __restrict__ featA,
                                              const float* __restrict__ cjA,
                                              const float* __restrict__ featB,
                                              const float* __restrict__ cjB,
                                              const ushort_t* __restrict__ Mt,
                                              ushort_t* __restrict__ gA,
                                              ushort_t* __restrict__ gB) {
    const float* feat; const float* cj; ushort_t* g;
    if (blockIdx.z == 0) { feat = featA; cj = cjA; g = gA; }
    else                 { feat = featB; cj = cjB; g = gB; }

    __shared__ ushort_t featS[64][136];
    __shared__ ushort_t mtS[160][136];

    const int tid  = threadIdx.x;
    const int row0 = blockIdx.x * 64;
    const int ch0  = blockIdx.y * 160;

    for (int i = tid; i < 64 * 32; i += 256) {
        int r  = i >> 5;
        int c4 = (i & 31) << 2;
        float4 v = make_float4(0.f, 0.f, 0.f, 0.f);
        int row = row0 + r;
        if (row < NDRUG) v = *(const float4*)(feat + (size_t)row * FF + c4);
        ushort4 pk;
        pk.x = f2bf(v.x); pk.y = f2bf(v.y); pk.z = f2bf(v.z); pk.w = f2bf(v.w);
        *(ushort4*)&featS[r][c4] = pk;
    }
    for (int i = tid; i < 160 * 16; i += 256) {
        int c  = i >> 4;
        int q8 = (i & 15) << 3;
        *(short8*)&mtS[c][q8] = *(const short8*)(Mt + (size_t)(ch0 + c) * FF + q8);
    }
    __syncthreads();

    const int w = tid >> 6;
    const int l = tid & 63;
    const int lr = l & 15;
    const int lg = l >> 4;

    short8 afrag[4];
#pragma unroll
    for (int ks = 0; ks < 4; ++ks)
        afrag[ks] = *(const short8*)&featS[w * 16 + lr][ks * 32 + lg * 8];

    const int rbase = row0 + w * 16 + (lg << 2);
    float cjv[4];
#pragma unroll
    for (int rg = 0; rg < 4; ++rg)
        cjv[rg] = (rbase + rg < NDRUG) ? cj[rbase + rg] : 0.f;

#pragma unroll
    for (int n = 0; n < 10; ++n) {
        f32x4 c = {0.f, 0.f, 0.f, 0.f};
#pragma unroll
        for (int ks = 0; ks < 4; ++ks) {
            short8 b = *(const short8*)&mtS[n * 16 + lr][ks * 32 + lg * 8];
            c = __builtin_amdgcn_mfma_f32_16x16x32_bf16(afrag[ks], b, c, 0, 0, 0);
        }
        int col = ch0 + n * 16 + lr;
#pragma unroll
        for (int rg = 0; rg < 4; ++rg) {
            int row = rbase + rg;
            if (row < NDRUG)
                g[(size_t)row * NCOL + col] = f2bf(c[rg] * cjv[rg]);
        }
    }
}

// ---------------------------------------------------------------------------
// Pass 1: coarse partition. Append packed entry ((dst&255)<<16 | src) into
// slotted bucket (dir, r, dst>>8) at stride CAP. Tail counters + tail data
// lines are XCD-local (partition p = dir*4 + dst-quarter, p = blockIdx.x&7),
// so appends write-combine in one L2 and each line is written back once.
// grid: (NCHUNKE*NPART, RR). dir 0: dst=edge_dis,src=edge_drug; dir 1: swapped.
// ---------------------------------------------------------------------------
__global__ __launch_bounds__(256) void k_part(const int* __restrict__ ed,
                                              const int* __restrict__ ei,
                                              int* __restrict__ tails,
                                              uint_t* __restrict__ coarse) {
    int p = blockIdx.x & (NPART - 1);
    int dir = p >> 2;
    int quarter = p & 3;
    int chunk = blockIdx.x >> 3;
    int r = blockIdx.y;
    const int* dstarr = (dir ? ed : ei) + (size_t)r * EE;
    const int* srcarr = (dir ? ei : ed) + (size_t)r * EE;
    int* tl = tails + (dir * RR + r) * NBKT;
    uint_t* cb = coarse + (size_t)(dir * RR + r) * NBKT * CAP;
    int blo = quarter * QBKT, bhi = blo + QBKT;
    int e0 = chunk * CHUNKE;
    for (int i = e0 + threadIdx.x; i < e0 + CHUNKE; i += 256) {
        int d = __builtin_nontemporal_load(dstarr + i);
        int b = d >> 8;
        if (b >= blo && b < bhi) {
            int src = __builtin_nontemporal_load(srcarr + i);
            int pos = atomicAdd(&tl[b], 1);
            if (pos < CAP)
                cb[(size_t)b * CAP + pos] = ((uint_t)(d & 255) << 16) | (uint_t)(ushort_t)src;
        }
    }
}

// ---------------------------------------------------------------------------
// Pass 2: fine counting sort within each bucket (one block per bucket).
// Reads bucket entries twice (seq), LDS 256-bin hist + scan, writes the
// sorted 2B src entries into the bucket's own contiguous slot window and the
// absolute end-offsets into bins[]. All global writes are block-local dense.
// grid: (NBKT, RR, 2)
// ---------------------------------------------------------------------------
__global__ __launch_bounds__(256) void k_fine(const uint_t* __restrict__ coarse,
                                              const int* __restrict__ tails,
                                              ushort_t* __restrict__ sorted,
                                              int* __restrict__ bins) {
    int b = blockIdx.x, r = blockIdx.y, dir = blockIdx.z;
    int gb = (dir * RR + r) * NBKT + b;
    size_t base = (size_t)gb * CAP;
    int count = tails[gb]; if (count > CAP) count = CAP;
    int t = threadIdx.x;

    __shared__ int cnt[256];
    __shared__ int incl[256];
    __shared__ int cur[256];

    cnt[t] = 0;
    __syncthreads();
    for (int i = t; i < count; i += 256)
        atomicAdd(&cnt[coarse[base + i] >> 16], 1);
    __syncthreads();

    int v = cnt[t];
    incl[t] = v;
    __syncthreads();
    for (int off = 1; off < 256; off <<= 1) {
        int x = (t >= off) ? incl[t - off] : 0;
        __syncthreads();
        incl[t] += x;
        __syncthreads();
    }
    int excl = incl[t] - v;
    cur[t] = excl;

    int d = b * 256 + t;
    if (d < NDIS)
        bins[dir * NB + r * NDIS + d] = (int)base + incl[t];   // absolute inclusive end
    __syncthreads();

    for (int i = t; i < count; i += 256) {
        uint_t e = coarse[base + i];
        int p = atomicAdd(&cur[e >> 16], 1);
        sorted[base + p] = (ushort_t)e;
    }
}

// ---------------------------------------------------------------------------
// Gather aggregation + fused epilogue. One wave per (dst, r) bin.
// bins[dir][k] = absolute inclusive end in the slotted sorted array;
// start = bins[k-1] except at bucket boundaries (dst&255==0) where
// start = bucket base (gb*CAP).
// ---------------------------------------------------------------------------
__global__ __launch_bounds__(256) void k_agg(const ushort_t* __restrict__ gd,
                                             const ushort_t* __restrict__ gi,
                                             const int* __restrict__ bins,
                                             const ushort_t* __restrict__ sorted,
                                             const float* __restrict__ ci_drug,
                                             const float* __restrict__ ci_dis,
                                             const float* __restrict__ fcb,
                                             float* __restrict__ out_drug,
                                             float* __restrict__ out_dis) {
    int dir = blockIdx.y;
    const ushort_t* g   = dir ? gi : gd;
    const float* ci     = dir ? ci_drug : ci_dis;
    float* outp         = dir ? out_drug : out_dis;
    const int* bn       = bins + dir * NB;

    int wave = blockIdx.x * 4 + (threadIdx.x >> 6);
    int lane = threadIdx.x & 63;
    if (wave >= NB) return;
    int r = wave / NDIS;
    int dst = wave - r * NDIS;
    int gb = (dir * RR + r) * NBKT + (dst >> 8);
    int start = (dst & 255) ? bn[wave - 1] : gb * CAP;
    int end = bn[wave];
    int colbase = r * OUTD + lane;

    float acc = 0.f;
    for (int base = start; base < end; base += 64) {
        int m = end - base; if (m > 64) m = 64;
        int li = lane < m ? lane : m - 1;
        int my = (int)sorted[(size_t)base + li];
        for (int j = 0; j < m; j += 8) {
            float part = 0.f;
#pragma unroll
            for (int k = 0; k < 8; ++k) {
                int jj = j + k;
                int cl = jj < m ? jj : m - 1;        // wave-uniform
                int sj = __shfl(my, cl);
                float v = bf2f(g[(size_t)sj * NCOL + colbase]);
                part += (jj < m) ? v : 0.f;
            }
            acc += part;
        }
    }
    outp[(size_t)dst * NCOL + colbase] = acc * ci[dst] + fcb[lane];
}

// ---------------------------------------------------------------------------
extern "C" void kernel_launch(void* const* d_in, const int* in_sizes, int n_in,
                              void* d_out, int out_size, void* d_ws, size_t ws_size,
                              hipStream_t stream) {
    const float* drug_feat = (const float*)d_in[0];
    const float* dis_feat  = (const float*)d_in[1];
    const float* cj_drug   = (const float*)d_in[2];
    const float* ci_drug   = (const float*)d_in[3];
    const float* cj_dis    = (const float*)d_in[4];
    const float* ci_dis    = (const float*)d_in[5];
    const float* att       = (const float*)d_in[6];
    const float* basis     = (const float*)d_in[7];
    const float* fcw       = (const float*)d_in[8];
    const float* fcb       = (const float*)d_in[9];
    const int*   edge_drug = (const int*)d_in[10];
    const int*   edge_dis  = (const int*)d_in[11];

    float* out      = (float*)d_out;
    float* out_drug = out;
    float* out_dis  = out + (size_t)NDRUG * NCOL;

    // Workspace layout (~114.4 MB):
    //   gd (bf16)   32,000,000 @ 0
    //   gi (bf16)   32,000,000 @ 32,000,000
    //   Mt (bf16)      163,840 @ 64,000,000
    //   bins (int)   2,000,000 @ 64,200,000
    //   tails (int)      7,840 @ 66,200,000
    //   coarse (u32) 32,112,640 @ 66,208,000
    //   sorted (u16) 16,056,320 @ 98,320,640
    char* ws = (char*)d_ws;
    ushort_t* gd      = (ushort_t*)ws;
    ushort_t* gi      = (ushort_t*)(ws + 32000000);
    ushort_t* Mtb     = (ushort_t*)(ws + 64000000);
    int*      bins    = (int*)(ws + 64200000);
    int*      tails   = (int*)(ws + 66200000);
    uint_t*   coarse  = (uint_t*)(ws + 66208000);
    ushort_t* sorted  = (ushort_t*)(ws + 98320640);

    // zero bucket tails
    hipMemsetAsync(tails, 0, NGB * sizeof(int), stream);

    // A: fused att*basis*fc_w -> Mt bf16 [320][128]
    k_make_M<<<dim3((RR * FF * OUTD + 255) / 256), 256, 0, stream>>>(att, basis, fcw, Mtb);

    // B: g = bf16((feat @ M) * cj), both sides (MFMA)
    dim3 ggrid((NDRUG + 63) / 64, 2, 2);
    k_gemm<<<ggrid, 256, 0, stream>>>(drug_feat, cj_drug, dis_feat, cj_dis, Mtb, gd, gi);

    // Two-level bucket sort (dense writes, no global scan)
    k_part<<<dim3(NCHUNKE * NPART, RR), 256, 0, stream>>>(edge_drug, edge_dis, tails, coarse);
    k_fine<<<dim3(NBKT, RR, 2), 256, 0, stream>>>(coarse, tails, sorted, bins);

    // Gather aggregation + fused ci-scale + bias
    k_agg<<<dim3((NB + 3) / 4, 2), 256, 0, stream>>>(gd, gi, bins, sorted,
                                                     ci_drug, ci_dis, fcb,
                                                     out_drug, out_dis);
}

// Round 9
// 349.332 us; speedup vs baseline: 2.8922x; 2.8922x over previous
//
#include <hip/hip_runtime.h>

// Problem constants
#define NDRUG 50000
#define NDIS  50000
#define RR    5
#define FF    128
#define EFFD  128
#define OUTD  64
#define EE    400000
#define NCOL  (RR * OUTD)        // 320 columns in fused g / out layout [n][r*64+o]
#define NB    (RR * NDIS)        // 250000 bins per direction
#define NEDGE (RR * EE)          // 2,000,000 edges per direction

// Two-level bucket sort
#define NBKT    196              // coarse buckets per (dir,r): dst>>8 (50000/256)
#define CAP     4096             // slot capacity per bucket (avg fill 2048, ~45 sigma headroom)
#define NGB     (2 * RR * NBKT)  // 1960 global buckets
#define QBKT    49               // buckets per dst-quarter (196 = 4*49)
#define STCAP   2048             // LDS staging entries per block (mean 1568, ~14 sigma)

// XCD partitioning for k_part: 8 partitions = dir(2) x dst-quarter(4)
#define NPART   8
#define NCHUNKE 64               // edge chunks per r
#define CHUNKE  (EE / NCHUNKE)   // 6250 edges per chunk

typedef unsigned short ushort_t;
typedef unsigned int uint_t;
typedef short short8 __attribute__((ext_vector_type(8)));
typedef float f32x4 __attribute__((ext_vector_type(4)));

// f32 -> bf16 round-to-nearest-even
static __device__ __forceinline__ ushort_t f2bf(float f) {
    uint_t u = __float_as_uint(f);
    uint_t r = (u + 0x7FFFu + ((u >> 16) & 1u)) >> 16;
    return (ushort_t)r;
}
static __device__ __forceinline__ float bf2f(ushort_t u) {
    return __uint_as_float(((uint_t)u) << 16);
}

// ---------------------------------------------------------------------------
// Kernel A: Mt[col][f] = bf16( sum_e (att[r,0]*basis[0,f,e]+att[r,1]*basis[1,f,e]) * fc_w[e,o] )
// ---------------------------------------------------------------------------
__global__ __launch_bounds__(256) void k_make_M(const float* __restrict__ att,
                                                const float* __restrict__ basis,
                                                const float* __restrict__ fcw,
                                                ushort_t* __restrict__ Mt) {
    int tid = blockIdx.x * 256 + threadIdx.x;
    if (tid >= RR * FF * OUTD) return;
    int r = tid / (FF * OUTD);
    int rem = tid - r * FF * OUTD;
    int f = rem >> 6;
    int o = rem & 63;
    float a0 = att[r * 2 + 0], a1 = att[r * 2 + 1];
    const float* b0 = basis + f * EFFD;
    const float* b1 = basis + FF * EFFD + f * EFFD;
    float acc = 0.f;
#pragma unroll 4
    for (int e = 0; e < EFFD; ++e) {
        float w = a0 * b0[e] + a1 * b1[e];
        acc += w * fcw[e * OUTD + o];
    }
    Mt[(size_t)(r * OUTD + o) * FF + f] = f2bf(acc);
}

// ---------------------------------------------------------------------------
// Kernel B (MFMA): g[n][col] = bf16( cj[n] * sum_k feat[n][k] * M[k][col] )
// ---------------------------------------------------------------------------
__global__ __launch_bounds__(256) void k_gemm(const float* __restrict__ featA,
                                              const float* __restrict__ cjA,
                                              const float* __restrict__ featB,
                                              const float* __restrict__ cjB,
                                              const ushort_t* __restrict__ Mt,
                                              ushort_t* __restrict__ gA,
                                              ushort_t* __restrict__ gB) {
    const float* feat; const float* cj; ushort_t* g;
    if (blockIdx.z == 0) { feat = featA; cj = cjA; g = gA; }
    else                 { feat = featB; cj = cjB; g = gB; }

    __shared__ ushort_t featS[64][136];
    __shared__ ushort_t mtS[160][136];

    const int tid  = threadIdx.x;
    const int row0 = blockIdx.x * 64;
    const int ch0  = blockIdx.y * 160;

    for (int i = tid; i < 64 * 32; i += 256) {
        int r  = i >> 5;
        int c4 = (i & 31) << 2;
        float4 v = make_float4(0.f, 0.f, 0.f, 0.f);
        int row = row0 + r;
        if (row < NDRUG) v = *(const float4*)(feat + (size_t)row * FF + c4);
        ushort4 pk;
        pk.x = f2bf(v.x); pk.y = f2bf(v.y); pk.z = f2bf(v.z); pk.w = f2bf(v.w);
        *(ushort4*)&featS[r][c4] = pk;
    }
    for (int i = tid; i < 160 * 16; i += 256) {
        int c  = i >> 4;
        int q8 = (i & 15) << 3;
        *(short8*)&mtS[c][q8] = *(const short8*)(Mt + (size_t)(ch0 + c) * FF + q8);
    }
    __syncthreads();

    const int w = tid >> 6;
    const int l = tid & 63;
    const int lr = l & 15;
    const int lg = l >> 4;

    short8 afrag[4];
#pragma unroll
    for (int ks = 0; ks < 4; ++ks)
        afrag[ks] = *(const short8*)&featS[w * 16 + lr][ks * 32 + lg * 8];

    const int rbase = row0 + w * 16 + (lg << 2);
    float cjv[4];
#pragma unroll
    for (int rg = 0; rg < 4; ++rg)
        cjv[rg] = (rbase + rg < NDRUG) ? cj[rbase + rg] : 0.f;

#pragma unroll
    for (int n = 0; n < 10; ++n) {
        f32x4 c = {0.f, 0.f, 0.f, 0.f};
#pragma unroll
        for (int ks = 0; ks < 4; ++ks) {
            short8 b = *(const short8*)&mtS[n * 16 + lr][ks * 32 + lg * 8];
            c = __builtin_amdgcn_mfma_f32_16x16x32_bf16(afrag[ks], b, c, 0, 0, 0);
        }
        int col = ch0 + n * 16 + lr;
#pragma unroll
        for (int rg = 0; rg < 4; ++rg) {
            int row = rbase + rg;
            if (row < NDRUG)
                g[(size_t)row * NCOL + col] = f2bf(c[rg] * cjv[rg]);
        }
    }
}

// ---------------------------------------------------------------------------
// Pass 1: coarse partition with BLOCK-LOCAL aggregation.
// Each block: (a) scans its edge chunk, staging matched edges in LDS via
// wave-ballot compaction (few LDS atomics), counting per-bucket in LDS;
// (b) ONE global atomicAdd per bucket to bulk-reserve a window (125K global
// atomics total instead of 4M); (c) writes each bucket's entries as a
// contiguous run -> every 64B line is produced by one block, back-to-back.
// grid: (NCHUNKE*NPART, RR); p = blockIdx.x&7 encodes dir=p>>2, quarter=p&3.
// ---------------------------------------------------------------------------
__global__ __launch_bounds__(256) void k_part(const int* __restrict__ ed,
                                              const int* __restrict__ ei,
                                              int* __restrict__ tails,
                                              uint_t* __restrict__ coarse) {
    int p = blockIdx.x & (NPART - 1);
    int dir = p >> 2;
    int quarter = p & 3;
    int chunk = blockIdx.x >> 3;
    int r = blockIdx.y;
    const int* dstarr = (dir ? ed : ei) + (size_t)r * EE;
    const int* srcarr = (dir ? ei : ed) + (size_t)r * EE;
    int* tl = tails + (dir * RR + r) * NBKT;
    uint_t* cb = coarse + (size_t)(dir * RR + r) * NBKT * CAP;
    int blo = quarter * QBKT;

    __shared__ uint_t stage[STCAP];
    __shared__ int cnt[QBKT];
    __shared__ int cur[QBKT];
    __shared__ int gpos[QBKT];
    __shared__ int nstage;

    int t = threadIdx.x;
    if (t < QBKT) { cnt[t] = 0; cur[t] = 0; }
    if (t == 0) nstage = 0;
    __syncthreads();

    int lane = t & 63;
    int e0 = chunk * CHUNKE;
    for (int i = e0 + t; i < e0 + CHUNKE; i += 256) {
        int d = __builtin_nontemporal_load(dstarr + i);
        int b = (d >> 8) - blo;
        bool m = ((unsigned)b < (unsigned)QBKT);
        unsigned long long mask = __ballot(m);
        if (mask) {
            int src = m ? __builtin_nontemporal_load(srcarr + i) : 0;
            int nw = __popcll(mask);
            int prefix = __popcll(mask & ((1ull << lane) - 1ull));
            int leader = (int)__ffsll((unsigned long long)mask) - 1;
            int wbase = 0;
            if (lane == leader) wbase = atomicAdd(&nstage, nw);
            wbase = __shfl(wbase, leader);
            if (m) {
                int idx = wbase + prefix;
                if (idx < STCAP) {
                    stage[idx] = ((uint_t)b << 26) | ((uint_t)(d & 255) << 16)
                               | (uint_t)(ushort_t)src;
                    atomicAdd(&cnt[b], 1);
                }
            }
        }
    }
    __syncthreads();

    if (t < QBKT) gpos[t] = atomicAdd(&tl[blo + t], cnt[t]);
    __syncthreads();

    int n = nstage; if (n > STCAP) n = STCAP;
    for (int i = t; i < n; i += 256) {
        uint_t e = stage[i];
        int b = e >> 26;
        int q = atomicAdd(&cur[b], 1);
        int idx = gpos[b] + q;
        if (idx < CAP)
            cb[(size_t)(blo + b) * CAP + idx] = e & 0x00FFFFFFu;
    }
}

// ---------------------------------------------------------------------------
// Pass 2: fine counting sort within each bucket (one block per bucket).
// grid: (NBKT, RR, 2)
// ---------------------------------------------------------------------------
__global__ __launch_bounds__(256) void k_fine(const uint_t* __restrict__ coarse,
                                              const int* __restrict__ tails,
                                              ushort_t* __restrict__ sorted,
                                              int* __restrict__ bins) {
    int b = blockIdx.x, r = blockIdx.y, dir = blockIdx.z;
    int gb = (dir * RR + r) * NBKT + b;
    size_t base = (size_t)gb * CAP;
    int count = tails[gb]; if (count > CAP) count = CAP;
    int t = threadIdx.x;

    __shared__ int cnt[256];
    __shared__ int incl[256];
    __shared__ int cur[256];

    cnt[t] = 0;
    __syncthreads();
    for (int i = t; i < count; i += 256)
        atomicAdd(&cnt[coarse[base + i] >> 16], 1);
    __syncthreads();

    int v = cnt[t];
    incl[t] = v;
    __syncthreads();
    for (int off = 1; off < 256; off <<= 1) {
        int x = (t >= off) ? incl[t - off] : 0;
        __syncthreads();
        incl[t] += x;
        __syncthreads();
    }
    int excl = incl[t] - v;
    cur[t] = excl;

    int d = b * 256 + t;
    if (d < NDIS)
        bins[dir * NB + r * NDIS + d] = (int)base + incl[t];   // absolute inclusive end
    __syncthreads();

    for (int i = t; i < count; i += 256) {
        uint_t e = coarse[base + i];
        int p = atomicAdd(&cur[e >> 16], 1);
        sorted[base + p] = (ushort_t)e;
    }
}

// ---------------------------------------------------------------------------
// Gather aggregation + fused epilogue. One wave per (dst, r) bin.
// bins[dir][k] = absolute inclusive end in the slotted sorted array;
// start = bins[k-1] except at bucket boundaries (dst&255==0) where
// start = bucket base (gb*CAP).
// ---------------------------------------------------------------------------
__global__ __launch_bounds__(256) void k_agg(const ushort_t* __restrict__ gd,
                                             const ushort_t* __restrict__ gi,
                                             const int* __restrict__ bins,
                                             const ushort_t* __restrict__ sorted,
                                             const float* __restrict__ ci_drug,
                                             const float* __restrict__ ci_dis,
                                             const float* __restrict__ fcb,
                                             float* __restrict__ out_drug,
                                             float* __restrict__ out_dis) {
    int dir = blockIdx.y;
    const ushort_t* g   = dir ? gi : gd;
    const float* ci     = dir ? ci_drug : ci_dis;
    float* outp         = dir ? out_drug : out_dis;
    const int* bn       = bins + dir * NB;

    int wave = blockIdx.x * 4 + (threadIdx.x >> 6);
    int lane = threadIdx.x & 63;
    if (wave >= NB) return;
    int r = wave / NDIS;
    int dst = wave - r * NDIS;
    int gb = (dir * RR + r) * NBKT + (dst >> 8);
    int start = (dst & 255) ? bn[wave - 1] : gb * CAP;
    int end = bn[wave];
    int colbase = r * OUTD + lane;

    float acc = 0.f;
    for (int base = start; base < end; base += 64) {
        int m = end - base; if (m > 64) m = 64;
        int li = lane < m ? lane : m - 1;
        int my = (int)sorted[(size_t)base + li];
        for (int j = 0; j < m; j += 8) {
            float part = 0.f;
#pragma unroll
            for (int k = 0; k < 8; ++k) {
                int jj = j + k;
                int cl = jj < m ? jj : m - 1;        // wave-uniform
                int sj = __shfl(my, cl);
                float v = bf2f(g[(size_t)sj * NCOL + colbase]);
                part += (jj < m) ? v : 0.f;
            }
            acc += part;
        }
    }
    outp[(size_t)dst * NCOL + colbase] = acc * ci[dst] + fcb[lane];
}

// ---------------------------------------------------------------------------
extern "C" void kernel_launch(void* const* d_in, const int* in_sizes, int n_in,
                              void* d_out, int out_size, void* d_ws, size_t ws_size,
                              hipStream_t stream) {
    const float* drug_feat = (const float*)d_in[0];
    const float* dis_feat  = (const float*)d_in[1];
    const float* cj_drug   = (const float*)d_in[2];
    const float* ci_drug   = (const float*)d_in[3];
    const float* cj_dis    = (const float*)d_in[4];
    const float* ci_dis    = (const float*)d_in[5];
    const float* att       = (const float*)d_in[6];
    const float* basis     = (const float*)d_in[7];
    const float* fcw       = (const float*)d_in[8];
    const float* fcb       = (const float*)d_in[9];
    const int*   edge_drug = (const int*)d_in[10];
    const int*   edge_dis  = (const int*)d_in[11];

    float* out      = (float*)d_out;
    float* out_drug = out;
    float* out_dis  = out + (size_t)NDRUG * NCOL;

    // Workspace layout (~114.4 MB):
    //   gd (bf16)   32,000,000 @ 0
    //   gi (bf16)   32,000,000 @ 32,000,000
    //   Mt (bf16)      163,840 @ 64,000,000
    //   bins (int)   2,000,000 @ 64,200,000
    //   tails (int)      7,840 @ 66,200,000
    //   coarse (u32) 32,112,640 @ 66,208,000
    //   sorted (u16) 16,056,320 @ 98,320,640
    char* ws = (char*)d_ws;
    ushort_t* gd      = (ushort_t*)ws;
    ushort_t* gi      = (ushort_t*)(ws + 32000000);
    ushort_t* Mtb     = (ushort_t*)(ws + 64000000);
    int*      bins    = (int*)(ws + 64200000);
    int*      tails   = (int*)(ws + 66200000);
    uint_t*   coarse  = (uint_t*)(ws + 66208000);
    ushort_t* sorted  = (ushort_t*)(ws + 98320640);

    // zero bucket tails
    hipMemsetAsync(tails, 0, NGB * sizeof(int), stream);

    // A: fused att*basis*fc_w -> Mt bf16 [320][128]
    k_make_M<<<dim3((RR * FF * OUTD + 255) / 256), 256, 0, stream>>>(att, basis, fcw, Mtb);

    // B: g = bf16((feat @ M) * cj), both sides (MFMA)
    dim3 ggrid((NDRUG + 63) / 64, 2, 2);
    k_gemm<<<ggrid, 256, 0, stream>>>(drug_feat, cj_drug, dis_feat, cj_dis, Mtb, gd, gi);

    // Two-level bucket sort (dense writes, block-aggregated reservations)
    k_part<<<dim3(NCHUNKE * NPART, RR), 256, 0, stream>>>(edge_drug, edge_dis, tails, coarse);
    k_fine<<<dim3(NBKT, RR, 2), 256, 0, stream>>>(coarse, tails, sorted, bins);

    // Gather aggregation + fused ci-scale + bias
    k_agg<<<dim3((NB + 3) / 4, 2), 256, 0, stream>>>(gd, gi, bins, sorted,
                                                     ci_drug, ci_dis, fcb,
                                                     out_drug, out_dis);
}